// Round 14
// baseline (1174.143 us; speedup 1.0000x reference)
//
#include <hip/hip_runtime.h>

#define M_DIM 8192
#define K_DIM 4096
#define N_DIM 16384
#define KT 32   // K tiles of 128 (= one weight scale block)

typedef __attribute__((ext_vector_type(4))) int i32x4;
typedef __attribute__((ext_vector_type(4))) float f32x4;

__device__ __forceinline__ int pack4(int a, int b, int c, int d) {
  return (a & 255) | ((b & 255) << 8) | ((c & 255) << 16) | (d << 24);
}

// ---- pre-pass 1: x fp32 -> int8 per-row, sx[row] = rowmax/127 ------------
__global__ __launch_bounds__(256) void quant_x_kernel(const float* __restrict__ x,
    char* __restrict__ xq, float* __restrict__ sx) {
  const int row = blockIdx.x;
  const int tid = threadIdx.x;
  const float4* xr = reinterpret_cast<const float4*>(x + (size_t)row * K_DIM);
  float4 v[4];
  float m = 0.f;
#pragma unroll
  for (int j = 0; j < 4; ++j) {
    v[j] = xr[tid * 4 + j];
    m = fmaxf(m, fmaxf(fmaxf(fabsf(v[j].x), fabsf(v[j].y)),
                       fmaxf(fabsf(v[j].z), fabsf(v[j].w))));
  }
#pragma unroll
  for (int o = 32; o > 0; o >>= 1) m = fmaxf(m, __shfl_xor(m, o));
  __shared__ float wm[4];
  if ((tid & 63) == 0) wm[tid >> 6] = m;
  __syncthreads();
  m = fmaxf(fmaxf(wm[0], wm[1]), fmaxf(wm[2], wm[3]));
  const float r = (m > 0.f) ? 127.f / m : 0.f;
  i32x4 pk;
#pragma unroll
  for (int j = 0; j < 4; ++j)
    pk[j] = pack4((int)rintf(v[j].x * r), (int)rintf(v[j].y * r),
                  (int)rintf(v[j].z * r), (int)rintf(v[j].w * r));
  reinterpret_cast<i32x4*>(xq + (size_t)row * K_DIM)[tid] = pk;
  if (tid == 0) sx[row] = (m > 0.f) ? m / 127.f : 0.f;
}

// ---- pre-pass 2: w_q int32 -> int8 (exact) -------------------------------
__global__ void repack_w_kernel(const int* __restrict__ wq, char* __restrict__ w8, int n16) {
  int i = blockIdx.x * blockDim.x + threadIdx.x;
  const int stride = gridDim.x * blockDim.x;
  const int4* q = reinterpret_cast<const int4*>(wq);
  i32x4* o = reinterpret_cast<i32x4*>(w8);
  for (; i < n16; i += stride) {
    int4 a = q[4 * i], b = q[4 * i + 1], c = q[4 * i + 2], d = q[4 * i + 3];
    i32x4 r;
    r[0] = pack4(a.x, a.y, a.z, a.w);
    r[1] = pack4(b.x, b.y, b.z, b.w);
    r[2] = pack4(c.x, c.y, c.z, c.w);
    r[3] = pack4(d.x, d.y, d.z, d.w);
    o[i] = r;
  }
}

// ---- async global -> LDS, 16 B per lane ----------------------------------
__device__ __forceinline__ void gload16(const void* g, void* l) {
  __builtin_amdgcn_global_load_lds(
      (const __attribute__((address_space(1))) unsigned int*)g,
      (__attribute__((address_space(3))) unsigned int*)l, 16, 0, 0);
}

#define BAR() do { asm volatile("" ::: "memory"); \
                   __builtin_amdgcn_s_barrier();  \
                   asm volatile("" ::: "memory"); } while (0)

#define MFI(a, b, c) __builtin_amdgcn_mfma_i32_16x16x64_i8(a, b, c, 0, 0, 0)

// ---- 128x128x128 8-wave int8 GEMM, A-direct-from-global, B in LDS --------
// C = sx[row] * (sum_kb ws[nb][kb] * (Aq . Bq^T)_kb) + bias
// A fragments are wave-private 32-row panels: read straight from global
// (L1/L2-served, 64B/row segments, shared with the wc-partner wave) into 16
// transient regs -> LDS traffic is B-only (128 fb reads + 32KB staging per
// 2 block-tiles, was 192 reads + 64KB). r11 schedule otherwise: 2 barriers
// per tile, stage B(t+2) after drain+BAR, counted vmcnt(2).
__global__ __launch_bounds__(512, 4) void gemm_kernel(
    const char* __restrict__ Aq, const char* __restrict__ Bq,
    const float* __restrict__ ws, const float* __restrict__ sx,
    const float* __restrict__ bias, float* __restrict__ C) {
  // buf p (16K): B [128][128B] at p*16384. scale row (32 floats) at 32768.
  __shared__ __align__(128) char lds[32768 + 128];

  const int tid = threadIdx.x;
  const int lane = tid & 63, wid = tid >> 6;   // 8 waves
  const int wr = wid >> 1, wc = wid & 1;       // 4x2 wave grid, 32x64/wave

  // Supertile ordering: grid 8192 = 64(tm) x 128(tn) tiles.
  // Super = 16x16 tiles (A 8MB + B 8MB slice, L3-resident).
  const int bid = blockIdx.x;
  const int r = bid & 255;                 // block within super
  const int s = bid >> 8;                  // super id 0..31
  const int sm = s & 3, sn = s >> 2;       // 4 x 8 supers
  const int tm = sm * 16 + (r & 15);       // 0..63
  const int tn = sn * 16 + (r >> 4);       // 0..127

  // stage this block's scale row: ws[tn][0..32)
  if (tid < 32) *(float*)(lds + 32768 + tid * 4) = ws[tn * 32 + tid];

  // ---- B staging: per-lane pre-swizzled global source, linear LDS dest ---
  const int srow = tid >> 3;                         // 0..63
  const int kswz = ((tid & 7) ^ (srow & 7)) << 4;    // swizzled byte offset
  const char* bSrc = Bq + (size_t)(tn * 128 + srow) * K_DIM + kswz;
  const int ldst = wid << 10;                        // wave-uniform

#define STAGE_B(tt, g, b) gload16(bSrc + (size_t)(g)*64*K_DIM + (size_t)(tt)*128, \
                                  lds + (b)*16384 + (g)*8192 + ldst)

  // ---- fb addressing (swizzled): unit u stored at u^(row&7) --------------
  const int hi = lane >> 4, lo3 = lane & 7;
  const int aks0 = ((0 + hi) ^ lo3) << 4;   // kstep 0 (k 0..63)
  const int aks1 = ((4 + hi) ^ lo3) << 4;   // kstep 1 (k 64..127)
  const int boff = (wc * 64 + (lane & 15)) * 128;

  // ---- A-direct addressing: row = lane&15 of wave panel, 16B quarter -----
  // 16x16x64 A frag layout: row = lane&15, k-bytes [(lane>>4)*16, +16)
  const char* aW = Aq + (size_t)(tm * 128 + wr * 32 + (lane & 15)) * K_DIM
                      + ((lane >> 4) << 4);

  f32x4 accf[2][4] = {};

  // ---- prologue: stage B(0)->buf0, B(1)->buf1 ----------------------------
  STAGE_B(0, 0, 0); STAGE_B(0, 1, 0);
  STAGE_B(1, 0, 1); STAGE_B(1, 1, 1);
  asm volatile("s_waitcnt vmcnt(2) lgkmcnt(0)" ::: "memory");  // B(0)+scales in
  BAR();

  for (int t = 0; t < KT; ++t) {
    const int p = t & 1;
    const char* Bb = lds + p * 16384 + boff;
    const float csc = *(const float*)(lds + 32768 + (t << 2));

    // ---- fb: 8 ds_read_b128 from LDS -------------------------------------
    i32x4 fb[4][2];
#pragma unroll
    for (int ni = 0; ni < 4; ++ni) {
      fb[ni][0] = *(const i32x4*)(Bb + ni * 2048 + aks0);
      fb[ni][1] = *(const i32x4*)(Bb + ni * 2048 + aks1);
    }

    // ---- fa: 4 global_load_dwordx4 (A direct, no LDS) --------------------
    i32x4 fa[2][2];
#pragma unroll
    for (int mi = 0; mi < 2; ++mi) {
      fa[mi][0] = *(const i32x4*)(aW + (size_t)(mi * 16) * K_DIM + t * 128);
      fa[mi][1] = *(const i32x4*)(aW + (size_t)(mi * 16) * K_DIM + t * 128 + 64);
    }

    // ---- all fb reads done -> restage is safe after barrier --------------
    asm volatile("s_waitcnt lgkmcnt(0)" ::: "memory");
    BAR();
    if (t + 2 < KT) {
      STAGE_B(t + 2, 0, p); STAGE_B(t + 2, 1, p);
      // leave only B(t+2) in flight: A(t) + B(t+1) drained
      asm volatile("s_waitcnt vmcnt(2)" ::: "memory");
    } else {
      asm volatile("s_waitcnt vmcnt(0)" ::: "memory");
    }

    // ---- per mi-group: 8 MFMA, immediate rescale -------------------------
#pragma unroll
    for (int mi = 0; mi < 2; ++mi) {
      i32x4 q0, q1, q2, q3;
      const i32x4 z4 = {0, 0, 0, 0};
      __builtin_amdgcn_s_setprio(1);
      q0 = MFI(fa[mi][0], fb[0][0], z4);
      q1 = MFI(fa[mi][0], fb[1][0], z4);
      q2 = MFI(fa[mi][0], fb[2][0], z4);
      q3 = MFI(fa[mi][0], fb[3][0], z4);
      q0 = MFI(fa[mi][1], fb[0][1], q0);
      q1 = MFI(fa[mi][1], fb[1][1], q1);
      q2 = MFI(fa[mi][1], fb[2][1], q2);
      q3 = MFI(fa[mi][1], fb[3][1], q3);
      __builtin_amdgcn_s_setprio(0);
#pragma unroll
      for (int e = 0; e < 4; ++e) {
        accf[mi][0][e] += csc * (float)q0[e];
        accf[mi][1][e] += csc * (float)q1[e];
        accf[mi][2][e] += csc * (float)q2[e];
        accf[mi][3][e] += csc * (float)q3[e];
      }
    }

    if (t + 1 < KT) BAR();
  }

  // ---- epilogue: C/D layout col=lane&15, row=(lane>>4)*4+reg; NT stores --
  const int crow0 = tm * 128 + wr * 32 + ((lane >> 4) << 2);
  const int ccol0 = tn * 128 + wc * 64 + (lane & 15);
#pragma unroll
  for (int mi = 0; mi < 2; ++mi) {
    float sxv[4];
#pragma unroll
    for (int e = 0; e < 4; ++e) sxv[e] = sx[crow0 + mi * 16 + e];
#pragma unroll
    for (int ni = 0; ni < 4; ++ni) {
      const float bv = bias[ccol0 + ni * 16];
#pragma unroll
      for (int e = 0; e < 4; ++e)
        __builtin_nontemporal_store(
            sxv[e] * accf[mi][ni][e] + bv,
            &C[(size_t)(crow0 + mi * 16 + e) * N_DIM + ccol0 + ni * 16]);
    }
  }
}

extern "C" void kernel_launch(void* const* d_in, const int* in_sizes, int n_in,
                              void* d_out, int out_size, void* d_ws, size_t ws_size,
                              hipStream_t stream) {
  const float* x    = (const float*)d_in[0];
  const int*   wq   = (const int*)d_in[1];
  const float* wsc  = (const float*)d_in[2];
  const float* bias = (const float*)d_in[3];
  float* out = (float*)d_out;

  const size_t xq_bytes = (size_t)M_DIM * K_DIM;        // 32 MB
  const size_t sx_bytes = (size_t)M_DIM * 4;            // 32 KB
  const size_t w8_bytes = (size_t)N_DIM * K_DIM;        // 64 MB
  if (ws_size < xq_bytes + sx_bytes + w8_bytes) return;

  char*  xq  = (char*)d_ws;
  float* sxp = (float*)((char*)d_ws + xq_bytes);
  char*  w8  = (char*)d_ws + xq_bytes + sx_bytes;

  quant_x_kernel<<<M_DIM, 256, 0, stream>>>(x, xq, sxp);
  repack_w_kernel<<<2048, 256, 0, stream>>>(wq, w8, N_DIM * K_DIM / 16);
  gemm_kernel<<<(M_DIM / 128) * (N_DIM / 128), 512, 0, stream>>>(
      xq, w8, wsc, sxp, bias, out);
}